// Round 5
// baseline (440.059 us; speedup 1.0000x reference)
//
#include <hip/hip_runtime.h>

#define HID 2048
#define INTER 5632
#define KVW 256
#define NL 6
#define RMS_EPS 1e-6f

#define NB 256     // 1 block per CU -> all co-resident
#define NT 1024    // 16 waves

typedef unsigned int uint;

// ws layout: uint region [0, 4096) = barriers; floats after.
#define F_H     4096
#define F_QV    6144
#define F_CTX   8192
#define F_PART  10240    // 32*256
#define F_INTER 18432    // 5632
#define F_GSC   24064

// barrier lines (64 uints = 256B each)
#define GL_LEAF 0      // 16 lines
#define GL_ROOT 16
#define GL_GEN  17     // 16 lines
#define ML_ROOT 33
#define ML_GEN  34     // 8 lines

#define KEEP4(v) asm volatile("" :: "v"((v).x), "v"((v).y), "v"((v).z), "v"((v).w))

// ---------------- LLC (relaxed agent-scope) access ----------------
__device__ __forceinline__ float ld_llc(const float* p) {
    return __hip_atomic_load(p, __ATOMIC_RELAXED, __HIP_MEMORY_SCOPE_AGENT);
}
__device__ __forceinline__ void st_llc(float* p, float v) {
    __hip_atomic_store(p, v, __ATOMIC_RELAXED, __HIP_MEMORY_SCOPE_AGENT);
}
__device__ __forceinline__ uint ld_llc_u(const uint* p) {
    return __hip_atomic_load(p, __ATOMIC_RELAXED, __HIP_MEMORY_SCOPE_AGENT);
}

// ---------------- wave helpers ----------------
__device__ __forceinline__ float waveAllSum(float v) {
#pragma unroll
    for (int m = 32; m > 0; m >>= 1) v += __shfl_xor(v, m, 64);
    return v;
}
__device__ __forceinline__ float waveAllMax(float v) {
#pragma unroll
    for (int m = 32; m > 0; m >>= 1) v = fmaxf(v, __shfl_xor(v, m, 64));
    return v;
}
__device__ __forceinline__ float dot4(float4 a, float4 b, float acc) {
    acc = fmaf(a.x, b.x, acc);
    acc = fmaf(a.y, b.y, acc);
    acc = fmaf(a.z, b.z, acc);
    acc = fmaf(a.w, b.w, acc);
    return acc;
}

// ---------------- gentle-poll monotonic grid barrier ----------------
// Arrival: leaf fetch_add (16 spread lines) -> root fetch_add -> 16 gen
// replicas stored by the final arriver. Wait: ONE lane polls ONE line with
// s_sleep(16) (~0.4us) between polls -- no fabric storm (round-4's flaw was
// 64-lane s_sleep(1) polling = ~1e11 LLC loads/s). Monotonic, fence-free:
// __syncthreads drains vmcnt before the arrival add, so this block's sc1 data
// stores reached the LLC first; visibility chains through LLC serialization.
__device__ __forceinline__ void gbar_sync(uint* bar, int bid, uint phase) {
    __syncthreads();
    if (threadIdx.x == 0) {
        uint* leaf = bar + (GL_LEAF + (bid & 15)) * 64;
        bool releaser = false;
        uint la = __hip_atomic_fetch_add(leaf, 1u, __ATOMIC_RELAXED, __HIP_MEMORY_SCOPE_AGENT);
        if (la == phase * 16u + 15u) {
            uint ra = __hip_atomic_fetch_add(bar + GL_ROOT * 64, 1u, __ATOMIC_RELAXED, __HIP_MEMORY_SCOPE_AGENT);
            if (ra == phase * 16u + 15u) {
#pragma unroll
                for (int i = 0; i < 16; ++i)
                    __hip_atomic_store(bar + (GL_GEN + i) * 64, phase + 1u,
                                       __ATOMIC_RELAXED, __HIP_MEMORY_SCOPE_AGENT);
                releaser = true;
            }
        }
        if (!releaser) {
            const uint* gen = bar + (GL_GEN + (bid & 15)) * 64;
            while (ld_llc_u(gen) <= phase) __builtin_amdgcn_s_sleep(16);
        }
    }
    __syncthreads();
}

// 32-block mini-barrier, same scheme, finer sleep
__device__ __forceinline__ void mbar_sync(uint* bar, int bid, uint phase) {
    __syncthreads();
    if (threadIdx.x == 0) {
        bool releaser = false;
        uint ra = __hip_atomic_fetch_add(bar + ML_ROOT * 64, 1u, __ATOMIC_RELAXED, __HIP_MEMORY_SCOPE_AGENT);
        if (ra == phase * 32u + 31u) {
#pragma unroll
            for (int i = 0; i < 8; ++i)
                __hip_atomic_store(bar + (ML_GEN + i) * 64, phase + 1u,
                                   __ATOMIC_RELAXED, __HIP_MEMORY_SCOPE_AGENT);
            releaser = true;
        }
        if (!releaser) {
            const uint* gen = bar + (ML_GEN + (bid & 7)) * 64;
            while (ld_llc_u(gen) <= phase) __builtin_amdgcn_s_sleep(4);
        }
    }
    __syncthreads();
}

// rmsnorm(h, nw) -> xbuf[2048] (LDS); aux[0..16) scratch
__device__ __forceinline__ void block_rms_norm(const float* __restrict__ h,
                                               const float* __restrict__ nw,
                                               float* xbuf, float* aux) {
    const int tid = threadIdx.x, lane = tid & 63, wid = tid >> 6;
    const float a = ld_llc(h + 2 * tid), b = ld_llc(h + 2 * tid + 1);
    float ss = a * a + b * b;
    ss = waveAllSum(ss);
    if (lane == 0) aux[wid] = ss;
    __syncthreads();
    float tot = 0.f;
#pragma unroll
    for (int i = 0; i < 16; ++i) tot += aux[i];
    const float f = rsqrtf(tot * (1.0f / (float)HID) + RMS_EPS);
    xbuf[2 * tid]     = a * f * nw[2 * tid];
    xbuf[2 * tid + 1] = b * f * nw[2 * tid + 1];
    __syncthreads();
}

// ---------------- init ----------------
__global__ __launch_bounds__(1024) void k_init(const float* __restrict__ x,
                                               float* __restrict__ ws) {
    uint* bar = (uint*)ws;
#pragma unroll
    for (int k = 0; k < 4; ++k) bar[k * 1024 + threadIdx.x] = 0u;
    float* h = ws + F_H;
    h[threadIdx.x] = x[threadIdx.x];
    h[1024 + threadIdx.x] = x[1024 + threadIdx.x];
}

// ---------------- persistent backbone ----------------
__global__ __launch_bounds__(NT, 4) void k_backbone(
    const float* __restrict__ kvw,
    const float* __restrict__ n1w, const float* __restrict__ n2w,
    const float* __restrict__ q_w, const float* __restrict__ o_w,
    const float* __restrict__ shg_w,
    const float* __restrict__ g_w, const float* __restrict__ u_w,
    const float* __restrict__ dn_w,
    float* __restrict__ out, float* __restrict__ ws) {
    __shared__ float buf[5632];
    __shared__ float aux[64];

    uint*  bar     = (uint*)ws;
    float* h       = ws + F_H;
    float* qv      = ws + F_QV;
    float* ctx     = ws + F_CTX;
    float* partial = ws + F_PART;
    float* inter   = ws + F_INTER;
    float* gsc     = ws + F_GSC;

    const int bid  = blockIdx.x;
    const int tid  = threadIdx.x;
    const int lane = tid & 63, wid = tid >> 6;
    const int row8 = bid * 8 + (wid >> 1);   // this block's 8 hidden rows
    const int half = wid & 1;
    uint gp = 0, mp = 0;

    // prefetch layer-0 Wq rows (pinned so the compiler can't sink them)
    float4 qpre[4];
    {
        const float4* Qn = (const float4*)(q_w + (size_t)row8 * HID + half * 1024);
#pragma unroll
        for (int k = 0; k < 4; ++k) { qpre[k] = Qn[k * 64 + lane]; KEEP4(qpre[k]); }
    }

    for (int L = 0; L < NL; ++L) {
        const float* Wo = o_w  + (size_t)L * HID * HID;
        const float* Wg = g_w  + (size_t)L * INTER * HID;
        const float* Wu = u_w  + (size_t)L * INTER * HID;
        const float* Wd = dn_w + (size_t)L * HID * INTER;

        // ---- P1: qv = Wq @ rmsnorm(h, n1) (weights in registers) ----
        block_rms_norm(h, n1w + L * HID, buf, aux);
        {
            const float4* X4 = (const float4*)(buf + half * 1024);
            float acc = 0.f;
#pragma unroll
            for (int k = 0; k < 4; ++k) acc = dot4(qpre[k], X4[k * 64 + lane], acc);
            acc = waveAllSum(acc);
            if (lane == 0) aux[16 + wid] = acc;
            __syncthreads();
            if (tid < 8) st_llc(qv + bid * 8 + tid, aux[16 + 2 * tid] + aux[16 + 2 * tid + 1]);
        }
        gbar_sync(bar, bid, gp++);

        // ---- P2: attention on blocks 0..31 ----
        if (bid < 32) {
            // P2a: partial scores for this block's 64-row strip
            float* qs = buf;          // 64
            float* ps = buf + 64;     // 1024
            if (tid < 64) qs[tid] = ld_llc(qv + bid * 64 + tid);
            __syncthreads();
            const int j = tid & 255, q4 = tid >> 8;
            const float* kb = kvw + ((size_t)(bid * 64 + q4 * 16)) * KVW + j;
            float acc = 0.f;
#pragma unroll
            for (int r = 0; r < 16; ++r) acc = fmaf(qs[q4 * 16 + r], kb[(size_t)r * KVW], acc);
            ps[q4 * 256 + j] = acc;
            __syncthreads();
            if (tid < 256)
                st_llc(partial + bid * 256 + tid,
                       ps[tid] + ps[256 + tid] + ps[512 + tid] + ps[768 + tid]);
            mbar_sync(bar, bid, mp++);

            // P2b: reduce partials -> softmax -> ctx strip
            float* sp = buf;          // 1024
            float* pj = buf + 1024;   // 256
            {
                float s = 0.f;
#pragma unroll
                for (int b = 0; b < 8; ++b) s += ld_llc(partial + (q4 * 8 + b) * 256 + j);
                sp[q4 * 256 + j] = s;
            }
            __syncthreads();
            float sv = -3.4e38f;
            if (tid < 256) sv = sp[tid] + sp[256 + tid] + sp[512 + tid] + sp[768 + tid];
            float mx = waveAllMax(sv);
            if (lane == 0 && wid < 4) aux[wid] = mx;
            __syncthreads();
            mx = fmaxf(fmaxf(aux[0], aux[1]), fmaxf(aux[2], aux[3]));
            const float e = (tid < 256) ? __expf(sv - mx) : 0.f;
            float tsum = waveAllSum(e);
            if (lane == 0 && wid < 4) aux[8 + wid] = tsum;
            __syncthreads();
            const float den = aux[8] + aux[9] + aux[10] + aux[11];
            if (tid < 256) pj[tid] = e / den;
            __syncthreads();
            const float4* p4  = (const float4*)pj;
            const float4* kv4 = (const float4*)kvw;
#pragma unroll
            for (int r = 0; r < 4; ++r) {
                const int i = bid * 64 + wid * 4 + r;
                float a = dot4(kv4[(size_t)i * 64 + lane], p4[lane], 0.f);
                a = waveAllSum(a);
                if (lane == 0) st_llc(ctx + i, a);
            }
        }
        // all blocks: prefetch Wo rows during the attention bubble
        float4 wo[4];
        {
            const float4* Wr = (const float4*)(Wo + (size_t)row8 * HID + half * 1024);
#pragma unroll
            for (int k = 0; k < 4; ++k) { wo[k] = Wr[k * 64 + lane]; KEEP4(wo[k]); }
        }
        gbar_sync(bar, bid, gp++);

        // ---- P3: h[row] += Wo[row,:] @ ctx (Wo prefetched) ----
        {
            buf[2 * tid]     = ld_llc(ctx + 2 * tid);
            buf[2 * tid + 1] = ld_llc(ctx + 2 * tid + 1);
            __syncthreads();
            const float4* X4 = (const float4*)(buf + half * 1024);
            float acc = 0.f;
#pragma unroll
            for (int k = 0; k < 4; ++k) acc = dot4(wo[k], X4[k * 64 + lane], acc);
            acc = waveAllSum(acc);
            if (lane == 0) aux[16 + wid] = acc;
            __syncthreads();
            if (tid < 8) {
                const int r = bid * 8 + tid;
                st_llc(h + r, ld_llc(h + r) + aux[16 + 2 * tid] + aux[16 + 2 * tid + 1]);
            }
        }
        gbar_sync(bar, bid, gp++);

        // ---- P4: inter = silu(Wg@x2)*(Wu@x2); block 0 computes scalar gate ----
        block_rms_norm(h, n2w + L * HID, buf, aux);
        {
            float* res = buf + 2048;   // 44
            const float4* X4 = (const float4*)buf;
            for (int t = wid; t < 44; t += 16) {
                const int jj = bid * 22 + (t >> 1);
                const float4* Wr = (const float4*)(((t & 1) ? Wu : Wg) + (size_t)jj * HID);
                float acc = 0.f;
#pragma unroll
                for (int k = 0; k < 8; ++k) acc = dot4(Wr[k * 64 + lane], X4[k * 64 + lane], acc);
                acc = waveAllSum(acc);
                if (lane == 0) res[t] = acc;
            }
            if (bid == 0) {
                const float* sw = shg_w + L * HID;
                float pv = sw[2 * tid] * buf[2 * tid] + sw[2 * tid + 1] * buf[2 * tid + 1];
                pv = waveAllSum(pv);
                if (lane == 0) aux[32 + wid] = pv;
            }
            __syncthreads();
            if (tid < 22) {
                const float gv = res[2 * tid], uv = res[2 * tid + 1];
                st_llc(inter + bid * 22 + tid, gv / (1.f + __expf(-gv)) * uv);
            }
            if (bid == 0 && tid == 0) {
                float gl = 0.f;
#pragma unroll
                for (int i = 0; i < 16; ++i) gl += aux[32 + i];
                st_llc(gsc, 1.f / (1.f + __expf(-gl)));
            }
        }
        // prefetch the ENTIRE Wd chunk for this block (44 VGPRs, pinned)
        float4 dpre[11];
        {
            const float4* Dr = (const float4*)(Wd + (size_t)row8 * INTER + half * 2816);
#pragma unroll
            for (int k = 0; k < 11; ++k) { dpre[k] = Dr[k * 64 + lane]; KEEP4(dpre[k]); }
        }
        gbar_sync(bar, bid, gp++);

        // ---- P5: h[row] += g * (Wd[row,:] @ inter) (Wd prefetched) ----
        {
#pragma unroll
            for (int k = 0; k < 6; ++k) {
                const int idx = k * 1024 + tid;
                if (idx < INTER) buf[idx] = ld_llc(inter + idx);
            }
            __syncthreads();
            const float gg = ld_llc(gsc);
            const float4* I4 = (const float4*)(buf + half * 2816);
            float acc = 0.f;
#pragma unroll
            for (int k = 0; k < 11; ++k) acc = dot4(dpre[k], I4[k * 64 + lane], acc);
            acc = waveAllSum(acc);
            if (lane == 0) aux[16 + wid] = acc;
            __syncthreads();
            if (tid < 8) {
                const int r = bid * 8 + tid;
                const float v = ld_llc(h + r) + gg * (aux[16 + 2 * tid] + aux[16 + 2 * tid + 1]);
                if (L == NL - 1) out[r] = v;
                else st_llc(h + r, v);
            }
        }
        if (L < NL - 1) {
            // prefetch next layer's Wq rows before the layer-end barrier
            const float4* Qn = (const float4*)(q_w + (size_t)(L + 1) * HID * HID +
                                               (size_t)row8 * HID + half * 1024);
#pragma unroll
            for (int k = 0; k < 4; ++k) { qpre[k] = Qn[k * 64 + lane]; KEEP4(qpre[k]); }
            gbar_sync(bar, bid, gp++);
        }
    }
}

// ---------------- host ----------------
extern "C" void kernel_launch(void* const* d_in, const int* in_sizes, int n_in,
                              void* d_out, int out_size, void* d_ws, size_t ws_size,
                              hipStream_t stream) {
    const float* x     = (const float*)d_in[0];
    const float* kvw   = (const float*)d_in[1];
    const float* n1w   = (const float*)d_in[2];
    const float* n2w   = (const float*)d_in[3];
    const float* q_w   = (const float*)d_in[4];
    // d_in[5]=k_w, d_in[6]=v_w: dead in reference
    const float* o_w   = (const float*)d_in[7];
    // d_in[8]=router_w: dead
    const float* shg_w = (const float*)d_in[9];
    const float* g_w   = (const float*)d_in[10];
    const float* u_w   = (const float*)d_in[11];
    const float* dn_w  = (const float*)d_in[12];
    float* out = (float*)d_out;
    float* ws  = (float*)d_ws;

    k_init<<<1, 1024, 0, stream>>>(x, ws);
    k_backbone<<<NB, NT, 0, stream>>>(kvw, n1w, n2w, q_w, o_w, shg_w,
                                      g_w, u_w, dn_w, out, ws);
}